// Round 19
// baseline (523.142 us; speedup 1.0000x reference)
//
#include <hip/hip_runtime.h>

constexpr float F_Y0     = 0.28209479177387814f;
constexpr float F_CUTOFF = 4.6f;

typedef short short8 __attribute__((ext_vector_type(8)));
typedef float f32x4  __attribute__((ext_vector_type(4)));

__device__ __forceinline__ float siluf(float v) { return v / (1.0f + __expf(-v)); }

// gfx950 hardware packed fp32->bf16 (RNE): lo = cvt(a), hi = cvt(b)
__device__ __forceinline__ unsigned pk2(float a, float b) {
  unsigned r;
  asm("v_cvt_pk_bf16_f32 %0, %1, %2" : "=v"(r) : "v"(a), "v"(b));
  return r;
}
// extract bf16 half h (0=lo,1=hi) of dword d as fp32
__device__ __forceinline__ float xbf(unsigned d, int h) {
  return __uint_as_float(h ? (d & 0xffff0000u) : (d << 16));
}

union FragU { uint4 u; short8 s; };

__device__ __forceinline__ void load16(const float* p, float* r) {
  const float4* p4 = (const float4*)p;
#pragma unroll
  for (int i = 0; i < 4; i++) {
    float4 t = p4[i];
    r[4*i] = t.x; r[4*i+1] = t.y; r[4*i+2] = t.z; r[4*i+3] = t.w;
  }
}
__device__ __forceinline__ void store16(float* p, const float* r) {
  float4* p4 = (float4*)p;
#pragma unroll
  for (int i = 0; i < 4; i++) p4[i] = make_float4(r[4*i], r[4*i+1], r[4*i+2], r[4*i+3]);
}

// block-level sum of one float per thread -> part[blockIdx.x]
__device__ __forceinline__ void block_reduce_store(float v, float* part) {
  __shared__ float sred[4];
  int tid = threadIdx.x;
#pragma unroll
  for (int off = 32; off > 0; off >>= 1) v += __shfl_down(v, off, 64);
  if ((tid & 63) == 0) sred[tid >> 6] = v;
  __syncthreads();
  if (tid == 0) part[blockIdx.x] = sred[0] + sred[1] + sred[2] + sred[3];
}

// ---------------- per-edge precompute (+ CSR histogram fused) ----------------
__global__ __launch_bounds__(256) void k_pre(
    const int* __restrict__ species, const int* __restrict__ src, const int* __restrict__ dst,
    const float* __restrict__ rel_pos,
    float* __restrict__ dist_, float* __restrict__ scale_,
    int* __restrict__ cnt,
    float* __restrict__ coul_part, int E)
{
  int e = blockIdx.x * 256 + threadIdx.x;
  float ce = 0.0f;
  if (e < E) {
    float px = rel_pos[3*(size_t)e + 0];
    float py = rel_pos[3*(size_t)e + 1];
    float pz = rel_pos[3*(size_t)e + 2];
    float dist = sqrtf(px*px + py*py + pz*pz);
    float xc = dist * (1.0f / F_CUTOFF);
    bool in_cut = dist < F_CUTOFF;
    float x2 = in_cut ? xc * xc : 0.0f;
    x2 = fminf(x2, 1.0f - 1e-6f);
    float sc = in_cut ? __expf(3.0f - 3.0f / (1.0f - x2)) : 0.0f;
    dist_[e] = dist;
    scale_[e] = sc;
    atomicAdd(&cnt[dst[e]], 1);
    float Zu = (float)species[src[e]];
    float Zv = (float)species[dst[e]];
    float raw = 0.529f * Zu * Zv / (2.0f * dist);
    float au = 0.8854f * 0.529f / (__powf(Zu, 0.23f) + __powf(Zv, 0.23f));
    float xx = dist / au;
    float screen = 0.1818f   * __expf(-3.2f    * xx)
                 + 0.5099f   * __expf(-0.9423f * xx)
                 + 0.2802f   * __expf(-0.4028f * xx)
                 + 0.02817f  * __expf(-0.2016f * xx);
    ce = raw * screen * sc;
  }
  block_reduce_store(ce, coul_part);
}

// ---------------- fused CSR scan: one block, 1024 threads, 32 nodes/thread ----
__global__ __launch_bounds__(1024) void k_scan(
    const int* __restrict__ cnt, int* __restrict__ row_ptr, int* __restrict__ row_cur,
    int N, int E)
{
  __shared__ int s[1024];
  int tid = threadIdx.x;
  int base = tid * 32;
  int loc[32];
  int tot = 0;
#pragma unroll
  for (int i = 0; i < 32; i++) {
    loc[i] = tot;                    // exclusive within thread
    tot += cnt[base + i];
  }
  s[tid] = tot;
  __syncthreads();
  // block exclusive scan of 1024 totals
  for (int off = 1; off < 1024; off <<= 1) {
    int t = (tid >= off) ? s[tid - off] : 0;
    __syncthreads();
    s[tid] += t;
    __syncthreads();
  }
  int tbase = s[tid] - tot;          // exclusive
#pragma unroll
  for (int i = 0; i < 32; i++) {
    int rp = tbase + loc[i];
    row_ptr[base + i] = rp;
    row_cur[base + i] = rp;
  }
  if (tid == 0) row_ptr[N] = E;
}

__global__ __launch_bounds__(256) void k_scatter_perm(
    const int* __restrict__ dst, int* __restrict__ row_cur,
    int* __restrict__ perm, int E)
{
  int e = blockIdx.x * 256 + threadIdx.x;
  if (e >= E) return;
  int pos = atomicAdd(&row_cur[dst[e]], 1);
  perm[pos] = e;
}

__global__ __launch_bounds__(256) void k_permute(
    const int* __restrict__ perm,
    const int* __restrict__ src, const float* __restrict__ dist_, const float* __restrict__ scale_,
    int* __restrict__ srcP, float* __restrict__ distP, float* __restrict__ scaleP, int E)
{
  int i = blockIdx.x * 256 + threadIdx.x;
  if (i >= E) return;
  int e = perm[i];
  srcP[i]   = src[e];
  distP[i]  = dist_[e];
  scaleP[i] = scale_[e];
}

// ---------------- weight prepack: per layer 21 bf16 B-fragments ----------------
__global__ __launch_bounds__(256) void k_prepack(
    const float* __restrict__ kv_W3, const float* __restrict__ kv_b3,
    const float* __restrict__ fin_W3, const float* __restrict__ fin_b3,
    const float* __restrict__ kv_W2, const float* __restrict__ fin_W2,
    const float* __restrict__ kv_W1, const float* __restrict__ fin_W1,
    uint4* __restrict__ WF)
{
  int t = blockIdx.x * 256 + threadIdx.x;
  if (t >= 5 * 21 * 64) return;
  int lyr = t / (21 * 64);
  int rem = t - lyr * 21 * 64;
  int f = rem >> 6;
  int l = rem & 63;
  int qq = l >> 4;
  int o = l & 15;
  const float* W3 = (lyr < 4) ? (kv_W3 + (size_t)lyr * 32 * 256) : fin_W3;
  const float* B3 = (lyr < 4) ? (kv_b3 + (size_t)lyr * 256) : fin_b3;
  const float* W2 = (lyr < 4) ? (kv_W2 + (size_t)lyr * 32 * 32) : fin_W2;
  const float* W1 = (lyr < 4) ? (kv_W1 + (size_t)lyr * 16 * 32) : fin_W1;
  float v[8];
#pragma unroll
  for (int j = 0; j < 8; j++) {
    if (f < 16) {
      int kk = f * 32 + qq * 8 + j;
      int m = kk >> 4, i = kk & 15;
      v[j] = W3[m * 256 + o * 16 + i];
    } else if (f == 16) {
      int r = qq * 8 + j;
      int mp = r >> 4, i = r & 15;
      v[j] = mp ? 0.0f : B3[o * 16 + i];
    } else if (f < 19) {
      int c = f - 17;
      int k = qq * 8 + j;
      v[j] = W2[k * 32 + c * 16 + o];
    } else {
      int c = f - 19;
      int k = qq * 8 + j;
      v[j] = (k < 16) ? W1[k * 32 + c * 16 + o] : 0.0f;
    }
  }
  uint4 dw;
  dw.x = pk2(v[0], v[1]);
  dw.y = pk2(v[2], v[3]);
  dw.z = pk2(v[4], v[5]);
  dw.w = pk2(v[6], v[7]);
  WF[t] = dw;
}

// ---------------- node init ----------------
__global__ __launch_bounds__(256) void k_node_init(
    const int* __restrict__ species, const float* __restrict__ emb,
    const float* __restrict__ Wq0,
    float* __restrict__ x, float* __restrict__ q, int N)
{
  int n = blockIdx.x * 256 + threadIdx.x;
  if (n >= N) return;
  int sp = species[n] - 1;
  float xv[16];
  load16(emb + (size_t)sp * 16, xv);
  store16(x + (size_t)n * 16, xv);
  float qv[8];
#pragma unroll
  for (int h = 0; h < 8; h++) {
    float a = 0.f;
#pragma unroll
    for (int i = 0; i < 16; i++) a += Wq0[h * 16 + i] * xv[i];
    qv[h] = a;
  }
  float4* qp = (float4*)(q + (size_t)n * 8);
  qp[0] = make_float4(qv[0], qv[1], qv[2], qv[3]);
  qp[1] = make_float4(qv[4], qv[5], qv[6], qv[7]);
}

// XOR-swizzled P chunk address (stride 128 dw, bank = f(chunk') only)
__device__ __forceinline__ unsigned* Pch(unsigned* P, int row, int chunk) {
  return P + row * 128 + ((chunk ^ (row & 31)) << 2);
}

// ---------------- heavy edge conv (MFMA h1+h2+W3; kv out = packed bf16) ------
// 3 blocks/CU: avoids the L2 write-churn regime seen at 4 blocks/CU.
template <int MODE>
__global__ __launch_bounds__(256, 3) void k_edge_conv(
    const int* __restrict__ srcP,
    const float* __restrict__ scaleP, const float* __restrict__ distP,
    const float* __restrict__ xsum, const float* __restrict__ x,
    const float* __restrict__ W1, const float* __restrict__ B1,
    const float* __restrict__ B2,
    const uint4* __restrict__ WF,
    unsigned* __restrict__ kvB, int E)
{
  __shared__ unsigned smem[10240];               // 40960 B
  unsigned* P   = smem;                           // [0,8192) two-phase
  unsigned* h1P = smem;                           // [0,1280) bf16 h1 [edge][20dw]
  float*    xsS = (float*)(smem + 1280);          // [1280,2560)
  unsigned* efB = smem + 2560;                    // [2560,3328) bf16 ef [edge][12dw]
  float*    h2P = (float*)(smem + 8192);          // [8192,9472)
  unsigned* xsB = smem + 9472;                    // [9472,10240)

  int tid = threadIdx.x;
  int w = __builtin_amdgcn_readfirstlane(tid >> 6);
  int l = tid & 63;
  int quad = l >> 4;
  int lo = l & 15;
  int q4 = quad * 4;
  int eb = blockIdx.x * 64;
  int el = eb + l;

  // ---- phase A0: cooperative gather (4 threads per edge) ----
  {
    int e4 = tid >> 2, c4 = tid & 3;
    int s4 = srcP[eb + e4];
    float4 xv4 = ((const float4*)(x + (size_t)s4 * 16))[c4];
    *(float4*)&xsS[e4 * 20 + c4 * 4] = xv4;
    xsB[e4 * 12 + c4 * 2]     = pk2(xv4.x, xv4.y);
    xsB[e4 * 12 + c4 * 2 + 1] = pk2(xv4.z, xv4.w);
    if (MODE == 2) {
      float4 ev4 = ((const float4*)(xsum + (size_t)s4 * 16))[c4];
      if (c4 == 3) ev4.w += distP[eb + e4];
      efB[e4 * 12 + c4 * 2]     = pk2(ev4.x, ev4.y);
      efB[e4 * 12 + c4 * 2 + 1] = pk2(ev4.z, ev4.w);
    }
  }
  __syncthreads();   // S1: xsS/xsB/efB staged

  float xs[16];
  load16(&xsS[l * 20], xs);

  int arow = w * 16 + lo;

  // ---- h1 ----
  if (MODE == 0) {
    float dd = distP[el];
    float h1v[8];
#pragma unroll
    for (int jj = 0; jj < 8; jj++) {
      int m = w * 8 + jj;
      h1v[jj] = fmaxf(B1[m] + dd * W1[15 * 32 + m], 0.f);
    }
    uint4 hq;
    hq.x = pk2(h1v[0], h1v[1]);
    hq.y = pk2(h1v[2], h1v[3]);
    hq.z = pk2(h1v[4], h1v[5]);
    hq.w = pk2(h1v[6], h1v[7]);
    *(uint4*)&h1P[l * 20 + w * 4] = hq;
    __syncthreads();   // cross-wave h1P (MODE 0 only)
  } else {
    FragU a, b0, b1;
    uint4 r = *(const uint4*)&efB[arow * 12 + (quad & 1) * 4];
    uint4 z = make_uint4(0, 0, 0, 0);
    a.u = (quad >= 2) ? z : r;
    b0.u = WF[19 * 64 + l];
    b1.u = WF[20 * 64 + l];
    f32x4 c0 = {0.f, 0.f, 0.f, 0.f};
    f32x4 c1 = {0.f, 0.f, 0.f, 0.f};
    c0 = __builtin_amdgcn_mfma_f32_16x16x32_bf16(a.s, b0.s, c0, 0, 0, 0);
    c1 = __builtin_amdgcn_mfma_f32_16x16x32_bf16(a.s, b1.s, c1, 0, 0, 0);
    float b1a = B1[lo];
    float b1b = B1[16 + lo];
    unsigned short* h1h = (unsigned short*)h1P;
#pragma unroll
    for (int r2 = 0; r2 < 4; r2++) {
      int e = w * 16 + quad * 4 + r2;
      float v0 = fmaxf(c0[r2] + b1a, 0.f);
      float v1 = fmaxf(c1[r2] + b1b, 0.f);
      h1h[e * 40 + lo]      = (unsigned short)(pk2(v0, v0) & 0xffffu);
      h1h[e * 40 + 16 + lo] = (unsigned short)(pk2(v1, v1) & 0xffffu);
    }
  }

  // ---- h2 via MFMA; stage as bf16 pairs (m, m+16) ----
  {
    FragU a, b0, b1;
    a.u = *(const uint4*)&h1P[arow * 20 + q4];
    b0.u = WF[17 * 64 + l];
    b1.u = WF[18 * 64 + l];
    f32x4 hc0 = {0.f, 0.f, 0.f, 0.f};
    f32x4 hc1 = {0.f, 0.f, 0.f, 0.f};
    hc0 = __builtin_amdgcn_mfma_f32_16x16x32_bf16(a.s, b0.s, hc0, 0, 0, 0);
    hc1 = __builtin_amdgcn_mfma_f32_16x16x32_bf16(a.s, b1.s, hc1, 0, 0, 0);
    float b2a = B2[lo];
    float b2b = B2[16 + lo];
    unsigned* h2u = (unsigned*)h2P;
#pragma unroll
    for (int r = 0; r < 4; r++) {
      int e = w * 16 + quad * 4 + r;
      h2u[e * 20 + lo] = pk2(fmaxf(hc0[r] + b2a, 0.f), fmaxf(hc1[r] + b2b, 0.f));
    }
  }
  __syncthreads();   // S2: h2P ready; pre-P aliases consumed

  // ---- own-edge h2 (unpack bf16 pairs) ----
  float h2lo[16], h2hi[16];
  {
    const unsigned* h2u = (const unsigned*)h2P;
#pragma unroll
    for (int c = 0; c < 4; c++) {
      uint4 t = *(const uint4*)&h2u[l * 20 + c * 4];
      unsigned d[4] = {t.x, t.y, t.z, t.w};
#pragma unroll
      for (int k = 0; k < 4; k++) {
        h2lo[c * 4 + k] = __uint_as_float(d[k] << 16);
        h2hi[c * 4 + k] = __uint_as_float(d[k] & 0xffff0000u);
      }
    }
  }

  // ---- P half 0 (m = 0..15) ----
#pragma unroll
  for (int jj = 0; jj < 4; jj++) {
    int mloc = w * 4 + jj;
    float hm = h2lo[mloc];
    uint4 d0, d1;
    d0.x = pk2(hm*xs[0],  hm*xs[1]);  d0.y = pk2(hm*xs[2],  hm*xs[3]);
    d0.z = pk2(hm*xs[4],  hm*xs[5]);  d0.w = pk2(hm*xs[6],  hm*xs[7]);
    d1.x = pk2(hm*xs[8],  hm*xs[9]);  d1.y = pk2(hm*xs[10], hm*xs[11]);
    d1.z = pk2(hm*xs[12], hm*xs[13]); d1.w = pk2(hm*xs[14], hm*xs[15]);
    *(uint4*)Pch(P, l, mloc * 2)     = d0;
    *(uint4*)Pch(P, l, mloc * 2 + 1) = d1;
  }
  __syncthreads();   // S3: half 0 built

  f32x4 acc = {0.f, 0.f, 0.f, 0.f};
#pragma unroll
  for (int t = 0; t < 8; t++) {
    FragU a, b;
    a.u = *(const uint4*)Pch(P, arow, t * 4 + quad);
    b.u = WF[t * 64 + l];
    acc = __builtin_amdgcn_mfma_f32_16x16x32_bf16(a.s, b.s, acc, 0, 0, 0);
  }
  {
    FragU a, b;
    uint4 r = *(const uint4*)&xsB[arow * 12 + (quad & 1) * 4];
    uint4 z = make_uint4(0, 0, 0, 0);
    a.u = (quad >= 2) ? z : r;
    b.u = WF[16 * 64 + l];
    acc = __builtin_amdgcn_mfma_f32_16x16x32_bf16(a.s, b.s, acc, 0, 0, 0);
  }
  __syncthreads();   // S4: half-0 reads done

  // ---- P half 1 (m = 16..31) ----
#pragma unroll
  for (int jj = 0; jj < 4; jj++) {
    int mloc = w * 4 + jj;
    float hm = h2hi[mloc];
    uint4 d0, d1;
    d0.x = pk2(hm*xs[0],  hm*xs[1]);  d0.y = pk2(hm*xs[2],  hm*xs[3]);
    d0.z = pk2(hm*xs[4],  hm*xs[5]);  d0.w = pk2(hm*xs[6],  hm*xs[7]);
    d1.x = pk2(hm*xs[8],  hm*xs[9]);  d1.y = pk2(hm*xs[10], hm*xs[11]);
    d1.z = pk2(hm*xs[12], hm*xs[13]); d1.w = pk2(hm*xs[14], hm*xs[15]);
    *(uint4*)Pch(P, l, mloc * 2)     = d0;
    *(uint4*)Pch(P, l, mloc * 2 + 1) = d1;
  }
  __syncthreads();   // S5: half 1 built

#pragma unroll
  for (int t = 0; t < 8; t++) {
    FragU a, b;
    a.u = *(const uint4*)Pch(P, arow, t * 4 + quad);
    b.u = WF[(8 + t) * 64 + l];
    acc = __builtin_amdgcn_mfma_f32_16x16x32_bf16(a.s, b.s, acc, 0, 0, 0);
  }

  // ---- kv epilogue: scale, stage fp32 in h2P, pack bf16, coalesced store ----
#pragma unroll
  for (int r = 0; r < 4; r++) {
    int eloc = w * 16 + quad * 4 + r;
    float bsc = F_Y0 * scaleP[eb + eloc];
    h2P[eloc * 20 + lo] = acc[r] * bsc;
  }
  __syncthreads();   // S6
  if (tid < 128) {
    int e = tid >> 1, c = tid & 1;
    const float* row = &h2P[e * 20 + c * 8];
    uint4 pkd;
    pkd.x = pk2(row[0], row[1]);
    pkd.y = pk2(row[2], row[3]);
    pkd.z = pk2(row[4], row[5]);
    pkd.w = pk2(row[6], row[7]);
    ((uint4*)(kvB + (size_t)eb * 8))[tid] = pkd;
  }
}

// ---------------- fused softmax-gather + node update (32 threads/node) ----------------
// Phase 1: t32 = p*8+h (p in 0..3); each p covers edges j0+p, j0+p+4, ...;
// partials combined via shfl_xor 8 & 16 (within the node's 32-lane group).
// Phase 2: low 16 lanes compute one xn output each.
template <bool INIT>
__global__ __launch_bounds__(256) void k_agg_update(
    const int* __restrict__ row_ptr, const float* __restrict__ scaleP,
    const unsigned* __restrict__ kvB, const float* __restrict__ qin,
    const float* __restrict__ xin,
    const float* __restrict__ Wproj, const float* __restrict__ Wq_next,
    float* __restrict__ xout, float* __restrict__ qout, float* __restrict__ xsum, int N)
{
  __shared__ float sA[8 * 8];
  __shared__ float sX[8 * 17];
  __shared__ float sN[8 * 17];
  int tid = threadIdx.x;
  int nl = tid >> 5;                 // node slot 0..7
  int t32 = tid & 31;
  int h = t32 & 7;
  int p = t32 >> 3;
  int n = blockIdx.x * 8 + nl;
  int hd = h >> 1, hh = h & 1;

  float qh = qin[(size_t)n * 8 + h];
  int j0 = row_ptr[n], j1 = row_ptr[n + 1];
  float num = 0.f, den = 0.f;
  for (int j = j0 + p; j < j1; j += 4) {
    float val = xbf(kvB[(size_t)j * 8 + hd], hh);
    float key = xbf(kvB[(size_t)j * 8 + 4 + hd], hh);
    float lg = fminf(key * qh, 60.0f);
    float wv = scaleP[j] * __expf(lg);
    num += wv * val;
    den += wv;
  }
  num += __shfl_xor(num, 8, 64);  den += __shfl_xor(den, 8, 64);
  num += __shfl_xor(num, 16, 64); den += __shfl_xor(den, 16, 64);
  if (p == 0) sA[nl * 8 + h] = num / fmaxf(den, 1e-20f);
  if (t32 < 16) sX[nl * 17 + t32] = xin[(size_t)n * 16 + t32];
  __syncthreads();

  if (t32 < 16) {
    float cat[24];
#pragma unroll
    for (int j = 0; j < 8; j++) cat[j] = sA[nl * 8 + j];
#pragma unroll
    for (int j = 0; j < 16; j++) cat[8 + j] = sX[nl * 17 + j];
    float xn = 0.f;
#pragma unroll
    for (int j = 0; j < 24; j++) xn += Wproj[t32 * 24 + j] * cat[j];
    xout[(size_t)n * 16 + t32] = xn;
    if (INIT) {
      xsum[(size_t)n * 16 + t32] = xn;
    } else {
      xsum[(size_t)n * 16 + t32] += xn;
    }
    sN[nl * 17 + t32] = xn;
  }
  __syncthreads();

  if (t32 < 8) {
    float a = 0.f;
#pragma unroll
    for (int i = 0; i < 16; i++) a += Wq_next[h * 16 + i] * sN[nl * 17 + i];
    qout[(size_t)n * 8 + h] = a;
  }
}

// ---------------- fused feats gather + final MLP (16 threads/node) ----------------
__global__ __launch_bounds__(256) void k_feats_final(
    const int* __restrict__ row_ptr, const unsigned* __restrict__ kvB,
    const float* __restrict__ x,
    const int* __restrict__ species, const float* __restrict__ emb,
    const float* __restrict__ Wself,
    const float* __restrict__ mW1, const float* __restrict__ mb1,
    const float* __restrict__ mW2, const float* __restrict__ mb2,
    const float* __restrict__ mW3, const float* __restrict__ mb3,
    float* __restrict__ learn_part, int N)
{
  __shared__ float sX[16 * 20];
  __shared__ float sC[16 * 40];
  __shared__ float sH[16 * 20];
  int tid = threadIdx.x;
  int nl = tid >> 4;
  int o = tid & 15;
  int n = blockIdx.x * 16 + nl;
  int od = o >> 1, oh = o & 1;

  int j0 = row_ptr[n], j1 = row_ptr[n + 1];
  float ft = 0.f;
  for (int j = j0; j < j1; ++j) ft += xbf(kvB[(size_t)j * 8 + od], oh);

  if (o < 4) {
    float4 v = ((const float4*)(x + (size_t)n * 16))[o];
    *(float4*)&sX[nl * 20 + o * 4] = v;
  } else if (o < 8) {
    int sp = species[n] - 1;
    float4 v = ((const float4*)(emb + (size_t)sp * 16))[o - 4];
    *(float4*)&sC[nl * 40 + (o - 4) * 4] = v;
  }
  __syncthreads();

  float xv[16];
  load16(&sX[nl * 20], xv);
  float a = ft;
#pragma unroll
  for (int i = 0; i < 16; i++) a += Wself[o * 16 + i] * xv[i];
  sC[nl * 40 + 16 + o] = a;
  __syncthreads();

  float cat[32];
  load16(&sC[nl * 40], cat);
  load16(&sC[nl * 40 + 16], cat + 16);
  float hh = mb1[o];
#pragma unroll
  for (int k = 0; k < 32; k++) hh += cat[k] * mW1[k * 16 + o];
  hh = siluf(hh);
  sH[nl * 20 + o] = hh;
  __syncthreads();

  float hv[16];
  load16(&sH[nl * 20], hv);
  float h2 = mb2[o];
#pragma unroll
  for (int k = 0; k < 16; k++) h2 += hv[k] * mW2[k * 16 + o];
  h2 = siluf(h2);
  float contrib = h2 * mW3[o] + ((o == 0) ? mb3[0] : 0.f);
  block_reduce_store(contrib, learn_part);
}

// ---------------- final reduction ----------------
__global__ __launch_bounds__(256) void k_finalize(
    const float* __restrict__ coul_part, int nc,
    const float* __restrict__ learn_part, int nl,
    float* __restrict__ out)
{
  __shared__ float sred[4];
  int tid = threadIdx.x;
  float v = 0.f;
  for (int i = tid; i < nc; i += 256) v += coul_part[i];
  for (int i = tid; i < nl; i += 256) v += learn_part[i];
#pragma unroll
  for (int off = 32; off > 0; off >>= 1) v += __shfl_down(v, off, 64);
  if ((tid & 63) == 0) sred[tid >> 6] = v;
  __syncthreads();
  if (tid == 0) out[0] = sred[0] + sred[1] + sred[2] + sred[3];
}

extern "C" void kernel_launch(void* const* d_in, const int* in_sizes, int n_in,
                              void* d_out, int out_size, void* d_ws, size_t ws_size,
                              hipStream_t stream)
{
  const int*   species = (const int*)d_in[0];
  const int*   src     = (const int*)d_in[1];
  const int*   dst     = (const int*)d_in[2];
  const float* rel_pos = (const float*)d_in[3];
  const float* emb     = (const float*)d_in[4];
  const float* kv_W1   = (const float*)d_in[5];
  const float* kv_b1   = (const float*)d_in[6];
  const float* kv_W2   = (const float*)d_in[7];
  const float* kv_b2   = (const float*)d_in[8];
  const float* kv_W3   = (const float*)d_in[9];
  const float* kv_b3   = (const float*)d_in[10];
  const float* Wq      = (const float*)d_in[11];
  const float* Wproj   = (const float*)d_in[12];
  const float* fin_W1  = (const float*)d_in[13];
  const float* fin_b1  = (const float*)d_in[14];
  const float* fin_W2  = (const float*)d_in[15];
  const float* fin_b2  = (const float*)d_in[16];
  const float* fin_W3  = (const float*)d_in[17];
  const float* fin_b3  = (const float*)d_in[18];
  const float* Wself   = (const float*)d_in[19];
  const float* mlp_W1  = (const float*)d_in[20];
  const float* mlp_b1  = (const float*)d_in[21];
  const float* mlp_W2  = (const float*)d_in[22];
  const float* mlp_b2  = (const float*)d_in[23];
  const float* mlp_W3  = (const float*)d_in[24];
  const float* mlp_b3  = (const float*)d_in[25];

  const int N = in_sizes[0];
  const int E = in_sizes[1];
  const int nblk_e = (E + 255) / 256;
  const int nblk_n = (N + 255) / 256;
  const int nblk_f = N / 16;

  char* p = (char*)d_ws;
  auto alloc = [&](size_t bytes) -> void* {
    void* r = (void*)p;
    p += (bytes + 255) & ~(size_t)255;
    return r;
  };
  float*    dist_   = (float*)alloc((size_t)E * 4);
  float*    scale_  = (float*)alloc((size_t)E * 4);
  float*    distP   = (float*)alloc((size_t)E * 4);
  float*    scaleP  = (float*)alloc((size_t)E * 4);
  int*      srcP    = (int*)  alloc((size_t)E * 4);
  int*      perm    = (int*)  alloc((size_t)E * 4);
  unsigned* kvB     = (unsigned*)alloc((size_t)E * 8 * 4);
  float*    xA      = (float*)alloc((size_t)N * 16 * 4);
  float*    xB      = (float*)alloc((size_t)N * 16 * 4);
  float*    xsum    = (float*)alloc((size_t)N * 16 * 4);
  float*    q       = (float*)alloc((size_t)N * 8 * 4);
  int*      cnt     = (int*)  alloc((size_t)N * 4);
  int*      row_ptr = (int*)  alloc((size_t)(N + 1) * 4);
  int*      row_cur = (int*)  alloc((size_t)N * 4);
  uint4*    WF      = (uint4*)alloc((size_t)5 * 21 * 64 * 16);
  float*    coul_part  = (float*)alloc((size_t)nblk_e * 4);
  float*    learn_part = (float*)alloc((size_t)nblk_f * 4);

  dim3 blk(256);
  dim3 egrid(nblk_e);
  dim3 cgrid(E / 64);
  dim3 ngrid(nblk_n);
  dim3 augrid(N / 8);
  dim3 fgrid(nblk_f);

  hipMemsetAsync(cnt, 0, (size_t)N * 4, stream);

  k_prepack<<<dim3(27), blk, 0, stream>>>(kv_W3, kv_b3, fin_W3, fin_b3,
                                          kv_W2, fin_W2, kv_W1, fin_W1, WF);

  k_pre<<<egrid, blk, 0, stream>>>(species, src, dst, rel_pos, dist_, scale_,
                                   cnt, coul_part, E);
  k_scan<<<dim3(1), dim3(1024), 0, stream>>>(cnt, row_ptr, row_cur, N, E);
  k_scatter_perm<<<egrid, blk, 0, stream>>>(dst, row_cur, perm, E);
  k_permute<<<egrid, blk, 0, stream>>>(perm, src, dist_, scale_,
                                       srcP, distP, scaleP, E);

  k_node_init<<<ngrid, blk, 0, stream>>>(species, emb, Wq, xA, q, N);

  float* xin = xA;
  float* xout = xB;
  for (int l = 0; l < 4; l++) {
    const float* W1 = kv_W1 + (size_t)l * 16 * 32;
    const float* B1 = kv_b1 + (size_t)l * 32;
    const float* B2 = kv_b2 + (size_t)l * 32;
    const uint4* WFl = WF + (size_t)l * 21 * 64;
    const float* Wqn = Wq + (size_t)((l < 3) ? (l + 1) : 0) * 8 * 16;
    if (l == 0) {
      k_edge_conv<0><<<cgrid, blk, 0, stream>>>(srcP, scaleP, distP, xsum, xin,
                                                W1, B1, B2, WFl, kvB, E);
    } else {
      k_edge_conv<2><<<cgrid, blk, 0, stream>>>(srcP, scaleP, distP, xsum, xin,
                                                W1, B1, B2, WFl, kvB, E);
    }
    if (l == 0) {
      k_agg_update<true><<<augrid, blk, 0, stream>>>(row_ptr, scaleP, kvB, q, xin,
                                                     Wproj, Wqn, xout, q, xsum, N);
    } else {
      k_agg_update<false><<<augrid, blk, 0, stream>>>(row_ptr, scaleP, kvB, q, xin,
                                                      Wproj + (size_t)l * 16 * 24, Wqn,
                                                      xout, q, xsum, N);
    }
    float* tmp = xin; xin = xout; xout = tmp;
  }

  k_edge_conv<2><<<cgrid, blk, 0, stream>>>(srcP, scaleP, distP, xsum, xin,
                                            fin_W1, fin_b1, fin_b2,
                                            WF + (size_t)4 * 21 * 64, kvB, E);
  k_feats_final<<<fgrid, blk, 0, stream>>>(row_ptr, kvB, xin, species, emb, Wself,
                                           mlp_W1, mlp_b1, mlp_W2, mlp_b2, mlp_W3, mlp_b3,
                                           learn_part, N);
  k_finalize<<<dim3(1), blk, 0, stream>>>(coul_part, nblk_e, learn_part, nblk_f,
                                          (float*)d_out);
}

// Round 20
// 500.666 us; speedup vs baseline: 1.0449x; 1.0449x over previous
//
#include <hip/hip_runtime.h>

constexpr float F_Y0     = 0.28209479177387814f;
constexpr float F_CUTOFF = 4.6f;

typedef short short8 __attribute__((ext_vector_type(8)));
typedef float f32x4  __attribute__((ext_vector_type(4)));

__device__ __forceinline__ float siluf(float v) { return v / (1.0f + __expf(-v)); }

// gfx950 hardware packed fp32->bf16 (RNE): lo = cvt(a), hi = cvt(b)
__device__ __forceinline__ unsigned pk2(float a, float b) {
  unsigned r;
  asm("v_cvt_pk_bf16_f32 %0, %1, %2" : "=v"(r) : "v"(a), "v"(b));
  return r;
}
// extract bf16 half h (0=lo,1=hi) of dword d as fp32
__device__ __forceinline__ float xbf(unsigned d, int h) {
  return __uint_as_float(h ? (d & 0xffff0000u) : (d << 16));
}

union FragU { uint4 u; short8 s; };

__device__ __forceinline__ void load16(const float* p, float* r) {
  const float4* p4 = (const float4*)p;
#pragma unroll
  for (int i = 0; i < 4; i++) {
    float4 t = p4[i];
    r[4*i] = t.x; r[4*i+1] = t.y; r[4*i+2] = t.z; r[4*i+3] = t.w;
  }
}
__device__ __forceinline__ void store16(float* p, const float* r) {
  float4* p4 = (float4*)p;
#pragma unroll
  for (int i = 0; i < 4; i++) p4[i] = make_float4(r[4*i], r[4*i+1], r[4*i+2], r[4*i+3]);
}

// block-level sum of one float per thread -> part[blockIdx.x]
__device__ __forceinline__ void block_reduce_store(float v, float* part) {
  __shared__ float sred[4];
  int tid = threadIdx.x;
#pragma unroll
  for (int off = 32; off > 0; off >>= 1) v += __shfl_down(v, off, 64);
  if ((tid & 63) == 0) sred[tid >> 6] = v;
  __syncthreads();
  if (tid == 0) part[blockIdx.x] = sred[0] + sred[1] + sred[2] + sred[3];
}

// ---------------- per-edge precompute (+ CSR histogram fused) ----------------
__global__ __launch_bounds__(256) void k_pre(
    const int* __restrict__ species, const int* __restrict__ src, const int* __restrict__ dst,
    const float* __restrict__ rel_pos,
    float* __restrict__ dist_, float* __restrict__ scale_,
    int* __restrict__ cnt,
    float* __restrict__ coul_part, int E)
{
  int e = blockIdx.x * 256 + threadIdx.x;
  float ce = 0.0f;
  if (e < E) {
    float px = rel_pos[3*(size_t)e + 0];
    float py = rel_pos[3*(size_t)e + 1];
    float pz = rel_pos[3*(size_t)e + 2];
    float dist = sqrtf(px*px + py*py + pz*pz);
    float xc = dist * (1.0f / F_CUTOFF);
    bool in_cut = dist < F_CUTOFF;
    float x2 = in_cut ? xc * xc : 0.0f;
    x2 = fminf(x2, 1.0f - 1e-6f);
    float sc = in_cut ? __expf(3.0f - 3.0f / (1.0f - x2)) : 0.0f;
    dist_[e] = dist;
    scale_[e] = sc;
    atomicAdd(&cnt[dst[e]], 1);
    float Zu = (float)species[src[e]];
    float Zv = (float)species[dst[e]];
    float raw = 0.529f * Zu * Zv / (2.0f * dist);
    float au = 0.8854f * 0.529f / (__powf(Zu, 0.23f) + __powf(Zv, 0.23f));
    float xx = dist / au;
    float screen = 0.1818f   * __expf(-3.2f    * xx)
                 + 0.5099f   * __expf(-0.9423f * xx)
                 + 0.2802f   * __expf(-0.4028f * xx)
                 + 0.02817f  * __expf(-0.2016f * xx);
    ce = raw * screen * sc;
  }
  block_reduce_store(ce, coul_part);
}

// ---------------- CSR scans ----------------
__global__ __launch_bounds__(256) void k_scan1(
    const int* __restrict__ cnt, int* __restrict__ row_ptr, int* __restrict__ bsum)
{
  __shared__ int s[256];
  int tid = threadIdx.x;
  int n = blockIdx.x * 256 + tid;
  int v = cnt[n];
  s[tid] = v;
  __syncthreads();
#pragma unroll
  for (int off = 1; off < 256; off <<= 1) {
    int t = (tid >= off) ? s[tid - off] : 0;
    __syncthreads();
    s[tid] += t;
    __syncthreads();
  }
  row_ptr[n] = s[tid] - v;
  if (tid == 255) bsum[blockIdx.x] = s[255];
}

__global__ __launch_bounds__(128) void k_scan2(int* __restrict__ bsum, int* __restrict__ boff)
{
  __shared__ int s[128];
  int tid = threadIdx.x;
  int v = bsum[tid];
  s[tid] = v;
  __syncthreads();
#pragma unroll
  for (int off = 1; off < 128; off <<= 1) {
    int t = (tid >= off) ? s[tid - off] : 0;
    __syncthreads();
    s[tid] += t;
    __syncthreads();
  }
  boff[tid] = s[tid] - v;
}

__global__ __launch_bounds__(256) void k_scan3(
    int* __restrict__ row_ptr, int* __restrict__ row_cur,
    const int* __restrict__ boff, int N, int E)
{
  int n = blockIdx.x * 256 + threadIdx.x;
  int rp = row_ptr[n] + boff[blockIdx.x];
  row_ptr[n] = rp;
  row_cur[n] = rp;
  if (n == 0) row_ptr[N] = E;
}

__global__ __launch_bounds__(256) void k_scatter_perm(
    const int* __restrict__ dst, int* __restrict__ row_cur,
    int* __restrict__ perm, int E)
{
  int e = blockIdx.x * 256 + threadIdx.x;
  if (e >= E) return;
  int pos = atomicAdd(&row_cur[dst[e]], 1);
  perm[pos] = e;
}

__global__ __launch_bounds__(256) void k_permute(
    const int* __restrict__ perm,
    const int* __restrict__ src, const float* __restrict__ dist_, const float* __restrict__ scale_,
    int* __restrict__ srcP, float* __restrict__ distP, float* __restrict__ scaleP, int E)
{
  int i = blockIdx.x * 256 + threadIdx.x;
  if (i >= E) return;
  int e = perm[i];
  srcP[i]   = src[e];
  distP[i]  = dist_[e];
  scaleP[i] = scale_[e];
}

// ---------------- weight prepack: per layer 21 bf16 B-fragments ----------------
__global__ __launch_bounds__(256) void k_prepack(
    const float* __restrict__ kv_W3, const float* __restrict__ kv_b3,
    const float* __restrict__ fin_W3, const float* __restrict__ fin_b3,
    const float* __restrict__ kv_W2, const float* __restrict__ fin_W2,
    const float* __restrict__ kv_W1, const float* __restrict__ fin_W1,
    uint4* __restrict__ WF)
{
  int t = blockIdx.x * 256 + threadIdx.x;
  if (t >= 5 * 21 * 64) return;
  int lyr = t / (21 * 64);
  int rem = t - lyr * 21 * 64;
  int f = rem >> 6;
  int l = rem & 63;
  int qq = l >> 4;
  int o = l & 15;
  const float* W3 = (lyr < 4) ? (kv_W3 + (size_t)lyr * 32 * 256) : fin_W3;
  const float* B3 = (lyr < 4) ? (kv_b3 + (size_t)lyr * 256) : fin_b3;
  const float* W2 = (lyr < 4) ? (kv_W2 + (size_t)lyr * 32 * 32) : fin_W2;
  const float* W1 = (lyr < 4) ? (kv_W1 + (size_t)lyr * 16 * 32) : fin_W1;
  float v[8];
#pragma unroll
  for (int j = 0; j < 8; j++) {
    if (f < 16) {
      int kk = f * 32 + qq * 8 + j;
      int m = kk >> 4, i = kk & 15;
      v[j] = W3[m * 256 + o * 16 + i];
    } else if (f == 16) {
      int r = qq * 8 + j;
      int mp = r >> 4, i = r & 15;
      v[j] = mp ? 0.0f : B3[o * 16 + i];
    } else if (f < 19) {
      int c = f - 17;
      int k = qq * 8 + j;
      v[j] = W2[k * 32 + c * 16 + o];
    } else {
      int c = f - 19;
      int k = qq * 8 + j;
      v[j] = (k < 16) ? W1[k * 32 + c * 16 + o] : 0.0f;
    }
  }
  uint4 dw;
  dw.x = pk2(v[0], v[1]);
  dw.y = pk2(v[2], v[3]);
  dw.z = pk2(v[4], v[5]);
  dw.w = pk2(v[6], v[7]);
  WF[t] = dw;
}

// ---------------- node init (x, q0; semb read on-demand later) ----------------
__global__ __launch_bounds__(256) void k_node_init(
    const int* __restrict__ species, const float* __restrict__ emb,
    const float* __restrict__ Wq0,
    float* __restrict__ x, float* __restrict__ q, int N)
{
  int n = blockIdx.x * 256 + threadIdx.x;
  if (n >= N) return;
  int sp = species[n] - 1;
  float xv[16];
  load16(emb + (size_t)sp * 16, xv);
  store16(x + (size_t)n * 16, xv);
  float qv[8];
#pragma unroll
  for (int h = 0; h < 8; h++) {
    float a = 0.f;
#pragma unroll
    for (int i = 0; i < 16; i++) a += Wq0[h * 16 + i] * xv[i];
    qv[h] = a;
  }
  float4* qp = (float4*)(q + (size_t)n * 8);
  qp[0] = make_float4(qv[0], qv[1], qv[2], qv[3]);
  qp[1] = make_float4(qv[4], qv[5], qv[6], qv[7]);
}

// XOR-swizzled P chunk address (stride 128 dw, bank = f(chunk') only)
__device__ __forceinline__ unsigned* Pch(unsigned* P, int row, int chunk) {
  return P + row * 128 + ((chunk ^ (row & 31)) << 2);
}

// ---------------- heavy edge conv (MFMA h1+h2+W3; kv out = packed bf16) ------
// 3 blocks/CU: avoids the L2 write-churn regime seen at 4 blocks/CU.
template <int MODE>
__global__ __launch_bounds__(256, 3) void k_edge_conv(
    const int* __restrict__ srcP,
    const float* __restrict__ scaleP, const float* __restrict__ distP,
    const float* __restrict__ xsum, const float* __restrict__ x,
    const float* __restrict__ W1, const float* __restrict__ B1,
    const float* __restrict__ B2,
    const uint4* __restrict__ WF,
    unsigned* __restrict__ kvB, int E)
{
  __shared__ unsigned smem[10240];               // 40960 B
  unsigned* P   = smem;                           // [0,8192) two-phase
  unsigned* h1P = smem;                           // [0,1280) bf16 h1 [edge][20dw]
  float*    xsS = (float*)(smem + 1280);          // [1280,2560)
  unsigned* efB = smem + 2560;                    // [2560,3328) bf16 ef [edge][12dw]
  float*    h2P = (float*)(smem + 8192);          // [8192,9472)
  unsigned* xsB = smem + 9472;                    // [9472,10240)

  int tid = threadIdx.x;
  int w = __builtin_amdgcn_readfirstlane(tid >> 6);
  int l = tid & 63;
  int quad = l >> 4;
  int lo = l & 15;
  int q4 = quad * 4;
  int eb = blockIdx.x * 64;
  int el = eb + l;

  // ---- phase A0: cooperative gather (4 threads per edge) ----
  {
    int e4 = tid >> 2, c4 = tid & 3;
    int s4 = srcP[eb + e4];
    float4 xv4 = ((const float4*)(x + (size_t)s4 * 16))[c4];
    *(float4*)&xsS[e4 * 20 + c4 * 4] = xv4;
    xsB[e4 * 12 + c4 * 2]     = pk2(xv4.x, xv4.y);
    xsB[e4 * 12 + c4 * 2 + 1] = pk2(xv4.z, xv4.w);
    if (MODE == 2) {
      float4 ev4 = ((const float4*)(xsum + (size_t)s4 * 16))[c4];
      if (c4 == 3) ev4.w += distP[eb + e4];
      efB[e4 * 12 + c4 * 2]     = pk2(ev4.x, ev4.y);
      efB[e4 * 12 + c4 * 2 + 1] = pk2(ev4.z, ev4.w);
    }
  }
  __syncthreads();   // S1: xsS/xsB/efB staged

  float xs[16];
  load16(&xsS[l * 20], xs);

  int arow = w * 16 + lo;

  // ---- h1 ----
  if (MODE == 0) {
    float dd = distP[el];
    float h1v[8];
#pragma unroll
    for (int jj = 0; jj < 8; jj++) {
      int m = w * 8 + jj;
      h1v[jj] = fmaxf(B1[m] + dd * W1[15 * 32 + m], 0.f);
    }
    uint4 hq;
    hq.x = pk2(h1v[0], h1v[1]);
    hq.y = pk2(h1v[2], h1v[3]);
    hq.z = pk2(h1v[4], h1v[5]);
    hq.w = pk2(h1v[6], h1v[7]);
    *(uint4*)&h1P[l * 20 + w * 4] = hq;
    __syncthreads();   // cross-wave h1P (MODE 0 only)
  } else {
    FragU a, b0, b1;
    uint4 r = *(const uint4*)&efB[arow * 12 + (quad & 1) * 4];
    uint4 z = make_uint4(0, 0, 0, 0);
    a.u = (quad >= 2) ? z : r;
    b0.u = WF[19 * 64 + l];
    b1.u = WF[20 * 64 + l];
    f32x4 c0 = {0.f, 0.f, 0.f, 0.f};
    f32x4 c1 = {0.f, 0.f, 0.f, 0.f};
    c0 = __builtin_amdgcn_mfma_f32_16x16x32_bf16(a.s, b0.s, c0, 0, 0, 0);
    c1 = __builtin_amdgcn_mfma_f32_16x16x32_bf16(a.s, b1.s, c1, 0, 0, 0);
    float b1a = B1[lo];
    float b1b = B1[16 + lo];
    unsigned short* h1h = (unsigned short*)h1P;
#pragma unroll
    for (int r2 = 0; r2 < 4; r2++) {
      int e = w * 16 + quad * 4 + r2;
      float v0 = fmaxf(c0[r2] + b1a, 0.f);
      float v1 = fmaxf(c1[r2] + b1b, 0.f);
      h1h[e * 40 + lo]      = (unsigned short)(pk2(v0, v0) & 0xffffu);
      h1h[e * 40 + 16 + lo] = (unsigned short)(pk2(v1, v1) & 0xffffu);
    }
  }

  // ---- h2 via MFMA; stage as bf16 pairs (m, m+16) ----
  {
    FragU a, b0, b1;
    a.u = *(const uint4*)&h1P[arow * 20 + q4];
    b0.u = WF[17 * 64 + l];
    b1.u = WF[18 * 64 + l];
    f32x4 hc0 = {0.f, 0.f, 0.f, 0.f};
    f32x4 hc1 = {0.f, 0.f, 0.f, 0.f};
    hc0 = __builtin_amdgcn_mfma_f32_16x16x32_bf16(a.s, b0.s, hc0, 0, 0, 0);
    hc1 = __builtin_amdgcn_mfma_f32_16x16x32_bf16(a.s, b1.s, hc1, 0, 0, 0);
    float b2a = B2[lo];
    float b2b = B2[16 + lo];
    unsigned* h2u = (unsigned*)h2P;
#pragma unroll
    for (int r = 0; r < 4; r++) {
      int e = w * 16 + quad * 4 + r;
      h2u[e * 20 + lo] = pk2(fmaxf(hc0[r] + b2a, 0.f), fmaxf(hc1[r] + b2b, 0.f));
    }
  }
  __syncthreads();   // S2: h2P ready; pre-P aliases consumed

  // ---- own-edge h2 (unpack bf16 pairs) ----
  float h2lo[16], h2hi[16];
  {
    const unsigned* h2u = (const unsigned*)h2P;
#pragma unroll
    for (int c = 0; c < 4; c++) {
      uint4 t = *(const uint4*)&h2u[l * 20 + c * 4];
      unsigned d[4] = {t.x, t.y, t.z, t.w};
#pragma unroll
      for (int k = 0; k < 4; k++) {
        h2lo[c * 4 + k] = __uint_as_float(d[k] << 16);
        h2hi[c * 4 + k] = __uint_as_float(d[k] & 0xffff0000u);
      }
    }
  }

  // ---- P half 0 (m = 0..15) ----
#pragma unroll
  for (int jj = 0; jj < 4; jj++) {
    int mloc = w * 4 + jj;
    float hm = h2lo[mloc];
    uint4 d0, d1;
    d0.x = pk2(hm*xs[0],  hm*xs[1]);  d0.y = pk2(hm*xs[2],  hm*xs[3]);
    d0.z = pk2(hm*xs[4],  hm*xs[5]);  d0.w = pk2(hm*xs[6],  hm*xs[7]);
    d1.x = pk2(hm*xs[8],  hm*xs[9]);  d1.y = pk2(hm*xs[10], hm*xs[11]);
    d1.z = pk2(hm*xs[12], hm*xs[13]); d1.w = pk2(hm*xs[14], hm*xs[15]);
    *(uint4*)Pch(P, l, mloc * 2)     = d0;
    *(uint4*)Pch(P, l, mloc * 2 + 1) = d1;
  }
  __syncthreads();   // S3: half 0 built

  f32x4 acc = {0.f, 0.f, 0.f, 0.f};
#pragma unroll
  for (int t = 0; t < 8; t++) {
    FragU a, b;
    a.u = *(const uint4*)Pch(P, arow, t * 4 + quad);
    b.u = WF[t * 64 + l];
    acc = __builtin_amdgcn_mfma_f32_16x16x32_bf16(a.s, b.s, acc, 0, 0, 0);
  }
  {
    FragU a, b;
    uint4 r = *(const uint4*)&xsB[arow * 12 + (quad & 1) * 4];
    uint4 z = make_uint4(0, 0, 0, 0);
    a.u = (quad >= 2) ? z : r;
    b.u = WF[16 * 64 + l];
    acc = __builtin_amdgcn_mfma_f32_16x16x32_bf16(a.s, b.s, acc, 0, 0, 0);
  }
  __syncthreads();   // S4: half-0 reads done

  // ---- P half 1 (m = 16..31) ----
#pragma unroll
  for (int jj = 0; jj < 4; jj++) {
    int mloc = w * 4 + jj;
    float hm = h2hi[mloc];
    uint4 d0, d1;
    d0.x = pk2(hm*xs[0],  hm*xs[1]);  d0.y = pk2(hm*xs[2],  hm*xs[3]);
    d0.z = pk2(hm*xs[4],  hm*xs[5]);  d0.w = pk2(hm*xs[6],  hm*xs[7]);
    d1.x = pk2(hm*xs[8],  hm*xs[9]);  d1.y = pk2(hm*xs[10], hm*xs[11]);
    d1.z = pk2(hm*xs[12], hm*xs[13]); d1.w = pk2(hm*xs[14], hm*xs[15]);
    *(uint4*)Pch(P, l, mloc * 2)     = d0;
    *(uint4*)Pch(P, l, mloc * 2 + 1) = d1;
  }
  __syncthreads();   // S5: half 1 built

#pragma unroll
  for (int t = 0; t < 8; t++) {
    FragU a, b;
    a.u = *(const uint4*)Pch(P, arow, t * 4 + quad);
    b.u = WF[(8 + t) * 64 + l];
    acc = __builtin_amdgcn_mfma_f32_16x16x32_bf16(a.s, b.s, acc, 0, 0, 0);
  }

  // ---- kv epilogue: scale, stage fp32 in h2P, pack bf16, coalesced store ----
#pragma unroll
  for (int r = 0; r < 4; r++) {
    int eloc = w * 16 + quad * 4 + r;
    float bsc = F_Y0 * scaleP[eb + eloc];
    h2P[eloc * 20 + lo] = acc[r] * bsc;
  }
  __syncthreads();   // S6
  if (tid < 128) {
    int e = tid >> 1, c = tid & 1;
    const float* row = &h2P[e * 20 + c * 8];
    uint4 pkd;
    pkd.x = pk2(row[0], row[1]);
    pkd.y = pk2(row[2], row[3]);
    pkd.z = pk2(row[4], row[5]);
    pkd.w = pk2(row[6], row[7]);
    ((uint4*)(kvB + (size_t)eb * 8))[tid] = pkd;
  }
}

// ---------------- fused softmax-gather + node update (16 threads/node) ----------------
template <bool INIT>
__global__ __launch_bounds__(256) void k_agg_update(
    const int* __restrict__ row_ptr, const float* __restrict__ scaleP,
    const unsigned* __restrict__ kvB, const float* __restrict__ qin,
    const float* __restrict__ xin,
    const float* __restrict__ Wproj, const float* __restrict__ Wq_next,
    float* __restrict__ xout, float* __restrict__ qout, float* __restrict__ xsum, int N)
{
  __shared__ float sA[16 * 8];
  __shared__ float sX[16 * 17];
  __shared__ float sN[16 * 17];
  int tid = threadIdx.x;
  int nl = tid >> 4;
  int t16 = tid & 15;
  int h = t16 & 7;
  int p = t16 >> 3;
  int n = blockIdx.x * 16 + nl;
  int hd = h >> 1, hh = h & 1;

  float qh = qin[(size_t)n * 8 + h];
  int j0 = row_ptr[n], j1 = row_ptr[n + 1];
  float num = 0.f, den = 0.f;
  for (int j = j0 + p; j < j1; j += 2) {
    float val = xbf(kvB[(size_t)j * 8 + hd], hh);
    float key = xbf(kvB[(size_t)j * 8 + 4 + hd], hh);
    float lg = fminf(key * qh, 60.0f);
    float wv = scaleP[j] * __expf(lg);
    num += wv * val;
    den += wv;
  }
  num += __shfl_xor(num, 8, 64);
  den += __shfl_xor(den, 8, 64);
  if (p == 0) sA[nl * 8 + h] = num / fmaxf(den, 1e-20f);
  sX[nl * 17 + t16] = xin[(size_t)n * 16 + t16];
  __syncthreads();

  float cat[24];
#pragma unroll
  for (int j = 0; j < 8; j++) cat[j] = sA[nl * 8 + j];
#pragma unroll
  for (int j = 0; j < 16; j++) cat[8 + j] = sX[nl * 17 + j];
  float xn = 0.f;
#pragma unroll
  for (int j = 0; j < 24; j++) xn += Wproj[t16 * 24 + j] * cat[j];
  xout[(size_t)n * 16 + t16] = xn;
  if (INIT) {
    xsum[(size_t)n * 16 + t16] = xn;
  } else {
    xsum[(size_t)n * 16 + t16] += xn;
  }
  sN[nl * 17 + t16] = xn;
  __syncthreads();

  if (p == 0) {
    float a = 0.f;
#pragma unroll
    for (int i = 0; i < 16; i++) a += Wq_next[h * 16 + i] * sN[nl * 17 + i];
    qout[(size_t)n * 8 + h] = a;
  }
}

// ---------------- fused feats gather + final MLP (16 threads/node) ----------------
__global__ __launch_bounds__(256) void k_feats_final(
    const int* __restrict__ row_ptr, const unsigned* __restrict__ kvB,
    const float* __restrict__ x,
    const int* __restrict__ species, const float* __restrict__ emb,
    const float* __restrict__ Wself,
    const float* __restrict__ mW1, const float* __restrict__ mb1,
    const float* __restrict__ mW2, const float* __restrict__ mb2,
    const float* __restrict__ mW3, const float* __restrict__ mb3,
    float* __restrict__ learn_part, int N)
{
  __shared__ float sX[16 * 20];
  __shared__ float sC[16 * 40];
  __shared__ float sH[16 * 20];
  int tid = threadIdx.x;
  int nl = tid >> 4;
  int o = tid & 15;
  int n = blockIdx.x * 16 + nl;
  int od = o >> 1, oh = o & 1;

  int j0 = row_ptr[n], j1 = row_ptr[n + 1];
  float ft = 0.f;
  for (int j = j0; j < j1; ++j) ft += xbf(kvB[(size_t)j * 8 + od], oh);

  if (o < 4) {
    float4 v = ((const float4*)(x + (size_t)n * 16))[o];
    *(float4*)&sX[nl * 20 + o * 4] = v;
  } else if (o < 8) {
    int sp = species[n] - 1;
    float4 v = ((const float4*)(emb + (size_t)sp * 16))[o - 4];
    *(float4*)&sC[nl * 40 + (o - 4) * 4] = v;
  }
  __syncthreads();

  float xv[16];
  load16(&sX[nl * 20], xv);
  float a = ft;
#pragma unroll
  for (int i = 0; i < 16; i++) a += Wself[o * 16 + i] * xv[i];
  sC[nl * 40 + 16 + o] = a;
  __syncthreads();

  float cat[32];
  load16(&sC[nl * 40], cat);
  load16(&sC[nl * 40 + 16], cat + 16);
  float hh = mb1[o];
#pragma unroll
  for (int k = 0; k < 32; k++) hh += cat[k] * mW1[k * 16 + o];
  hh = siluf(hh);
  sH[nl * 20 + o] = hh;
  __syncthreads();

  float hv[16];
  load16(&sH[nl * 20], hv);
  float h2 = mb2[o];
#pragma unroll
  for (int k = 0; k < 16; k++) h2 += hv[k] * mW2[k * 16 + o];
  h2 = siluf(h2);
  float contrib = h2 * mW3[o] + ((o == 0) ? mb3[0] : 0.f);
  block_reduce_store(contrib, learn_part);
}

// ---------------- final reduction ----------------
__global__ __launch_bounds__(256) void k_finalize(
    const float* __restrict__ coul_part, int nc,
    const float* __restrict__ learn_part, int nl,
    float* __restrict__ out)
{
  __shared__ float sred[4];
  int tid = threadIdx.x;
  float v = 0.f;
  for (int i = tid; i < nc; i += 256) v += coul_part[i];
  for (int i = tid; i < nl; i += 256) v += learn_part[i];
#pragma unroll
  for (int off = 32; off > 0; off >>= 1) v += __shfl_down(v, off, 64);
  if ((tid & 63) == 0) sred[tid >> 6] = v;
  __syncthreads();
  if (tid == 0) out[0] = sred[0] + sred[1] + sred[2] + sred[3];
}

extern "C" void kernel_launch(void* const* d_in, const int* in_sizes, int n_in,
                              void* d_out, int out_size, void* d_ws, size_t ws_size,
                              hipStream_t stream)
{
  const int*   species = (const int*)d_in[0];
  const int*   src     = (const int*)d_in[1];
  const int*   dst     = (const int*)d_in[2];
  const float* rel_pos = (const float*)d_in[3];
  const float* emb     = (const float*)d_in[4];
  const float* kv_W1   = (const float*)d_in[5];
  const float* kv_b1   = (const float*)d_in[6];
  const float* kv_W2   = (const float*)d_in[7];
  const float* kv_b2   = (const float*)d_in[8];
  const float* kv_W3   = (const float*)d_in[9];
  const float* kv_b3   = (const float*)d_in[10];
  const float* Wq      = (const float*)d_in[11];
  const float* Wproj   = (const float*)d_in[12];
  const float* fin_W1  = (const float*)d_in[13];
  const float* fin_b1  = (const float*)d_in[14];
  const float* fin_W2  = (const float*)d_in[15];
  const float* fin_b2  = (const float*)d_in[16];
  const float* fin_W3  = (const float*)d_in[17];
  const float* fin_b3  = (const float*)d_in[18];
  const float* Wself   = (const float*)d_in[19];
  const float* mlp_W1  = (const float*)d_in[20];
  const float* mlp_b1  = (const float*)d_in[21];
  const float* mlp_W2  = (const float*)d_in[22];
  const float* mlp_b2  = (const float*)d_in[23];
  const float* mlp_W3  = (const float*)d_in[24];
  const float* mlp_b3  = (const float*)d_in[25];

  const int N = in_sizes[0];
  const int E = in_sizes[1];
  const int nblk_e = (E + 255) / 256;
  const int nblk_n = (N + 255) / 256;
  const int nblk_f = N / 16;

  char* p = (char*)d_ws;
  auto alloc = [&](size_t bytes) -> void* {
    void* r = (void*)p;
    p += (bytes + 255) & ~(size_t)255;
    return r;
  };
  float*    dist_   = (float*)alloc((size_t)E * 4);
  float*    scale_  = (float*)alloc((size_t)E * 4);
  float*    distP   = (float*)alloc((size_t)E * 4);
  float*    scaleP  = (float*)alloc((size_t)E * 4);
  int*      srcP    = (int*)  alloc((size_t)E * 4);
  int*      perm    = (int*)  alloc((size_t)E * 4);
  unsigned* kvB     = (unsigned*)alloc((size_t)E * 8 * 4);
  float*    xA      = (float*)alloc((size_t)N * 16 * 4);
  float*    xB      = (float*)alloc((size_t)N * 16 * 4);
  float*    xsum    = (float*)alloc((size_t)N * 16 * 4);
  float*    q       = (float*)alloc((size_t)N * 8 * 4);
  int*      cnt     = (int*)  alloc((size_t)N * 4);
  int*      row_ptr = (int*)  alloc((size_t)(N + 1) * 4);
  int*      row_cur = (int*)  alloc((size_t)N * 4);
  int*      bsum    = (int*)  alloc(128 * 4);
  int*      boff    = (int*)  alloc(128 * 4);
  uint4*    WF      = (uint4*)alloc((size_t)5 * 21 * 64 * 16);
  float*    coul_part  = (float*)alloc((size_t)nblk_e * 4);
  float*    learn_part = (float*)alloc((size_t)nblk_f * 4);

  dim3 blk(256);
  dim3 egrid(nblk_e);
  dim3 cgrid(E / 64);
  dim3 ngrid(nblk_n);
  dim3 augrid(N / 16);
  dim3 fgrid(nblk_f);

  hipMemsetAsync(cnt, 0, (size_t)N * 4, stream);

  k_prepack<<<dim3(27), blk, 0, stream>>>(kv_W3, kv_b3, fin_W3, fin_b3,
                                          kv_W2, fin_W2, kv_W1, fin_W1, WF);

  k_pre<<<egrid, blk, 0, stream>>>(species, src, dst, rel_pos, dist_, scale_,
                                   cnt, coul_part, E);
  k_scan1<<<ngrid, blk, 0, stream>>>(cnt, row_ptr, bsum);
  k_scan2<<<dim3(1), dim3(128), 0, stream>>>(bsum, boff);
  k_scan3<<<ngrid, blk, 0, stream>>>(row_ptr, row_cur, boff, N, E);
  k_scatter_perm<<<egrid, blk, 0, stream>>>(dst, row_cur, perm, E);
  k_permute<<<egrid, blk, 0, stream>>>(perm, src, dist_, scale_,
                                       srcP, distP, scaleP, E);

  k_node_init<<<ngrid, blk, 0, stream>>>(species, emb, Wq, xA, q, N);

  float* xin = xA;
  float* xout = xB;
  for (int l = 0; l < 4; l++) {
    const float* W1 = kv_W1 + (size_t)l * 16 * 32;
    const float* B1 = kv_b1 + (size_t)l * 32;
    const float* B2 = kv_b2 + (size_t)l * 32;
    const uint4* WFl = WF + (size_t)l * 21 * 64;
    const float* Wqn = Wq + (size_t)((l < 3) ? (l + 1) : 0) * 8 * 16;
    if (l == 0) {
      k_edge_conv<0><<<cgrid, blk, 0, stream>>>(srcP, scaleP, distP, xsum, xin,
                                                W1, B1, B2, WFl, kvB, E);
    } else {
      k_edge_conv<2><<<cgrid, blk, 0, stream>>>(srcP, scaleP, distP, xsum, xin,
                                                W1, B1, B2, WFl, kvB, E);
    }
    if (l == 0) {
      k_agg_update<true><<<augrid, blk, 0, stream>>>(row_ptr, scaleP, kvB, q, xin,
                                                     Wproj, Wqn, xout, q, xsum, N);
    } else {
      k_agg_update<false><<<augrid, blk, 0, stream>>>(row_ptr, scaleP, kvB, q, xin,
                                                      Wproj + (size_t)l * 16 * 24, Wqn,
                                                      xout, q, xsum, N);
    }
    float* tmp = xin; xin = xout; xout = tmp;
  }

  k_edge_conv<2><<<cgrid, blk, 0, stream>>>(srcP, scaleP, distP, xsum, xin,
                                            fin_W1, fin_b1, fin_b2,
                                            WF + (size_t)4 * 21 * 64, kvB, E);
  k_feats_final<<<fgrid, blk, 0, stream>>>(row_ptr, kvB, xin, species, emb, Wself,
                                           mlp_W1, mlp_b1, mlp_W2, mlp_b2, mlp_W3, mlp_b3,
                                           learn_part, N);
  k_finalize<<<dim3(1), blk, 0, stream>>>(coul_part, nblk_e, learn_part, nblk_f,
                                          (float*)d_out);
}